// Round 8
// baseline (474.143 us; speedup 1.0000x reference)
//
#include <hip/hip_runtime.h>

// y[e] = W2 . relu(W1 . concat(z[src[e]], z[dst[e]]) + b1) + b2
// N=50000, D=128, H=512, E=500000. Compute-bound: 131 GFLOP in GEMM1.
// R8: amortize the gather over ALL of H (R5) while keeping R7's 3-waves/SIMD
// register profile. Block = 64 edges x 4 waves; nc=2 passes (wave covers
// h = nc*256 + w*64 .. +64). GEMM2 partial accumulated in LDS (ldsY), NOT
// registers -> zero cross-pass reg state; per-pass profile == R7 (132 regs).
// nc loop forced unroll 1 so pass-2 B-loads can't be hoisted (R6 spill cause).
// Direct store (no atomics, no out-zeroing). LDS 35 KB -> 3 blocks/CU.

typedef __bf16 bf16x8 __attribute__((ext_vector_type(8)));
typedef float f32x4 __attribute__((ext_vector_type(4)));

#define STRA 264   // 256 + 8 pad (ushort units)

__device__ __forceinline__ unsigned short f2b(float f) {
    unsigned int u = __float_as_uint(f);
    u = (u + 0x7fffu + ((u >> 16) & 1u)) >> 16;   // RNE
    return (unsigned short)u;
}

// zb: z as bf16 [N][128].  w1s: W1 swizzled to MFMA-B fragment order:
// w1s[(hblk*8 + kc)*512 + lane*8 + t] = bf16(W1[hblk*16 + (lane&15)][kc*32 + (lane>>4)*8 + t])
__global__ void prep_kernel(const float* __restrict__ z, const float* __restrict__ W1,
                            unsigned short* __restrict__ zb, unsigned short* __restrict__ w1s,
                            int nz4) {
    int stride = gridDim.x * blockDim.x;
    const int nw = 256 * 64;   // (hblk*8+kc) x lane
    for (int idx = blockIdx.x * blockDim.x + threadIdx.x; idx < nz4 + nw; idx += stride) {
        if (idx < nz4) {
            float4 v = ((const float4*)z)[idx];
            ushort4 o;
            o.x = f2b(v.x); o.y = f2b(v.y); o.z = f2b(v.z); o.w = f2b(v.w);
            ((ushort4*)zb)[idx] = o;
        } else {
            int u = idx - nz4;            // 0..16383
            int lane = u & 63;
            int blk  = u >> 6;            // hblk*8 + kc
            int h  = (blk >> 3) * 16 + (lane & 15);
            int kb = (blk & 7) * 32 + (lane >> 4) * 8;
            const float* src = W1 + h * 256 + kb;
            ushort4 o0, o1;
            float4 v0 = *(const float4*)(src);
            float4 v1 = *(const float4*)(src + 4);
            o0.x = f2b(v0.x); o0.y = f2b(v0.y); o0.z = f2b(v0.z); o0.w = f2b(v0.w);
            o1.x = f2b(v1.x); o1.y = f2b(v1.y); o1.z = f2b(v1.z); o1.w = f2b(v1.w);
            ushort4* dst = (ushort4*)(w1s + u * 8);
            dst[0] = o0; dst[1] = o1;
        }
    }
}

__global__ __launch_bounds__(256, 3)
void edge_mlp_kernel(const int* __restrict__ ei, const unsigned short* __restrict__ zb,
                     const unsigned short* __restrict__ w1s,
                     const float* __restrict__ b1, const float* __restrict__ W2,
                     const float* __restrict__ b2p, float* __restrict__ out, int E) {
    __shared__ unsigned short ldsA[64 * STRA];  // 33792 B : 64 edges x 256 k (bf16)
    __shared__ int ldsIdx[128];                 // 64 edges x {src,dst}
    __shared__ float ldsY[4 * 64];              // per-wave GEMM2 partials

    const int tid  = threadIdx.x;
    const int lane = tid & 63;
    const int w    = tid >> 6;        // 0..3 : 64-h slice within each nc pass
    const int l15  = lane & 15;
    const int l4   = lane >> 4;
    const int ebase = blockIdx.x * 64;

    // ---- broadcast edge indices: one coalesced load -> LDS ----
    if (tid < 128) {
        int e = ebase + (tid >> 1);
        int side = tid & 1;
        ldsIdx[tid] = (e < E) ? ei[side * E + e] : 0;
    }
    __syncthreads();

    // ---- gather A: 64 edges x (z[src] ++ z[dst]) as bf16 rows ----
    {
        const int g = tid >> 4;     // 16 groups of 16 lanes
        const int l = tid & 15;
        #pragma unroll
        for (int it = 0; it < 8; ++it) {
            int hr = it * 16 + g;          // half-row 0..127
            int m = hr >> 1, side = hr & 1;
            int row = ldsIdx[hr];
            uint4 v = *((const uint4*)(zb + (row << 7)) + l);
            *(uint4*)&ldsA[m * STRA + side * 128 + l * 8] = v;
        }
    }
    __syncthreads();   // ldsA ready; read-only from here on

    const unsigned aoff = l15 * STRA + l4 * 8;

    #pragma unroll 1                  // keep passes separate (reg pressure!)
    for (int nc = 0; nc < 2; ++nc) {
        f32x4 acc[4][4];
        #pragma unroll
        for (int i = 0; i < 4; i++)
            #pragma unroll
            for (int j = 0; j < 4; j++) acc[i][j] = (f32x4){0.f, 0.f, 0.f, 0.f};

        // hblk = nc*16 + w*4 + j;  B frag at w1s[(hblk*8 + kc)*512 + lane*8]
        const unsigned short* bp = w1s + ((nc * 16 + w * 4) * 8) * 512 + lane * 8;

        #pragma unroll
        for (int kc = 0; kc < 8; ++kc) {
            uint4 b[4];
            #pragma unroll
            for (int j = 0; j < 4; j++)
                b[j] = *(const uint4*)(bp + (j * 8 + kc) * 512);
            bf16x8 a[4];
            #pragma unroll
            for (int i = 0; i < 4; i++)
                a[i] = *(const bf16x8*)&ldsA[aoff + i * 16 * STRA + kc * 32];
            #pragma unroll
            for (int i = 0; i < 4; i++)
                #pragma unroll
                for (int j = 0; j < 4; j++)
                    acc[i][j] = __builtin_amdgcn_mfma_f32_16x16x32_bf16(
                        a[i], *(const bf16x8*)&b[j], acc[i][j], 0, 0, 0);
        }

        // fused epilogue: h = relu(acc + b1); y = sum_h h * W2[h]
        float y[4][4];
        #pragma unroll
        for (int j = 0; j < 4; j++) {
            int h = nc * 256 + w * 64 + j * 16 + l15;
            float w2v = W2[h];
            float b1v = b1[h];
            #pragma unroll
            for (int i = 0; i < 4; i++)
                #pragma unroll
                for (int r = 0; r < 4; r++) {
                    float hv = acc[i][j][r] + b1v;
                    float t = fmaxf(hv, 0.f) * w2v;
                    y[i][r] = (j == 0) ? t : y[i][r] + t;
                }
        }

        // reduce over the 16 h-lanes (C layout: col = lane&15)
        #pragma unroll
        for (int i = 0; i < 4; i++)
            #pragma unroll
            for (int r = 0; r < 4; r++) {
                float v = y[i][r];
                v += __shfl_xor(v, 1);
                v += __shfl_xor(v, 2);
                v += __shfl_xor(v, 4);
                v += __shfl_xor(v, 8);
                y[i][r] = v;
            }

        // accumulate into per-wave LDS slot (no cross-wave hazard: slot [w])
        if (l15 == 0) {
            #pragma unroll
            for (int i = 0; i < 4; i++)
                #pragma unroll
                for (int r = 0; r < 4; r++) {
                    int m = i * 16 + l4 * 4 + r;   // C layout: row=(lane>>4)*4+reg
                    if (nc == 0) ldsY[w * 64 + m] = y[i][r];
                    else         ldsY[w * 64 + m] += y[i][r];
                }
        }
    }

    __syncthreads();
    if (tid < 64) {
        int e = ebase + tid;
        if (e < E)
            out[e] = ldsY[tid] + ldsY[64 + tid] + ldsY[128 + tid] + ldsY[192 + tid] + b2p[0];
    }
}

extern "C" void kernel_launch(void* const* d_in, const int* in_sizes, int n_in,
                              void* d_out, int out_size, void* d_ws, size_t ws_size,
                              hipStream_t stream) {
    const float* z  = (const float*)d_in[0];
    const int*   ei = (const int*)d_in[1];
    const float* W1 = (const float*)d_in[2];
    const float* b1 = (const float*)d_in[3];
    const float* W2 = (const float*)d_in[4];
    const float* b2 = (const float*)d_in[5];
    float* out = (float*)d_out;

    const int E  = in_sizes[1] / 2;   // 500000
    const int NZ = in_sizes[0];       // 6400000 = N*D

    unsigned short* zb  = (unsigned short*)d_ws;       // 12.8 MB
    unsigned short* w1s = zb + NZ;                     // 256 KB (swizzled W1)

    prep_kernel<<<2048, 256, 0, stream>>>(z, W1, zb, w1s, NZ / 4);

    const int blocks = (E + 63) / 64;                  // 7813
    edge_mlp_kernel<<<blocks, 256, 0, stream>>>(ei, zb, w1s, b1, W2, b2, out, E);
}

// Round 9
// 377.845 us; speedup vs baseline: 1.2549x; 1.2549x over previous
//
#include <hip/hip_runtime.h>

// y[e] = W2 . relu(W1 . concat(z[src[e]], z[dst[e]]) + b1) + b2
// N=50000, D=128, H=512, E=500000. Compute-bound: 131 GFLOP in GEMM1.
// R9: tile-level software pipelining. Each block (R7 profile: hy half of H,
// 64x64 wave tile, no nc loop, atomicAdd combine) processes 8 consecutive
// 64-edge tiles with DOUBLE-BUFFERED ldsA: gather(t+1) is issued right after
// the top barrier and its ~1-2k cyc latency hides under tile t's ~2.5k cyc
// K-loop. Serial gather leaves the critical path (paid once per 8 tiles).
// bounds(256,2) = known-safe register cap. LDS 68.6 KB -> 2 blocks/CU.

typedef __bf16 bf16x8 __attribute__((ext_vector_type(8)));
typedef float f32x4 __attribute__((ext_vector_type(4)));

#define STRA 264   // 256 + 8 pad (ushort units)
#define NT 8       // tiles of 64 edges per block

__device__ __forceinline__ unsigned short f2b(float f) {
    unsigned int u = __float_as_uint(f);
    u = (u + 0x7fffu + ((u >> 16) & 1u)) >> 16;   // RNE
    return (unsigned short)u;
}

// gather one 64-edge tile into an LDS buffer (no barrier inside).
// ei loads are 16-way duplicated (L1 broadcast) -> no LDS/idx barrier needed.
__device__ __forceinline__ void gather_tile(const int* __restrict__ ei,
                                            const unsigned short* __restrict__ zb,
                                            unsigned short* buf,
                                            int ebase, int E, int g, int l) {
    #pragma unroll
    for (int it = 0; it < 8; ++it) {
        int hr = it * 16 + g;          // half-row 0..127
        int m = hr >> 1, side = hr & 1;
        int e = ebase + m;
        int row = (e < E) ? ei[side * E + e] : 0;
        uint4 v = *((const uint4*)(zb + (row << 7)) + l);
        *(uint4*)&buf[m * STRA + side * 128 + l * 8] = v;
    }
}

// zb: z as bf16 [N][128].  w1s: W1 swizzled to MFMA-B fragment order:
// w1s[(hblk*8 + kc)*512 + lane*8 + t] = bf16(W1[hblk*16 + (lane&15)][kc*32 + (lane>>4)*8 + t])
// Also zeroes out[] (atomicAdd target).
__global__ void prep_kernel(const float* __restrict__ z, const float* __restrict__ W1,
                            unsigned short* __restrict__ zb, unsigned short* __restrict__ w1s,
                            float* __restrict__ outz, int nz4, int nout4) {
    int stride = gridDim.x * blockDim.x;
    const int nw = 256 * 64;   // (hblk*8+kc) x lane
    const int total = nz4 + nw + nout4;
    for (int idx = blockIdx.x * blockDim.x + threadIdx.x; idx < total; idx += stride) {
        if (idx < nz4) {
            float4 v = ((const float4*)z)[idx];
            ushort4 o;
            o.x = f2b(v.x); o.y = f2b(v.y); o.z = f2b(v.z); o.w = f2b(v.w);
            ((ushort4*)zb)[idx] = o;
        } else if (idx < nz4 + nw) {
            int u = idx - nz4;            // 0..16383
            int lane = u & 63;
            int blk  = u >> 6;            // hblk*8 + kc
            int h  = (blk >> 3) * 16 + (lane & 15);
            int kb = (blk & 7) * 32 + (lane >> 4) * 8;
            const float* src = W1 + h * 256 + kb;
            ushort4 o0, o1;
            float4 v0 = *(const float4*)(src);
            float4 v1 = *(const float4*)(src + 4);
            o0.x = f2b(v0.x); o0.y = f2b(v0.y); o0.z = f2b(v0.z); o0.w = f2b(v0.w);
            o1.x = f2b(v1.x); o1.y = f2b(v1.y); o1.z = f2b(v1.z); o1.w = f2b(v1.w);
            ushort4* dst = (ushort4*)(w1s + u * 8);
            dst[0] = o0; dst[1] = o1;
        } else {
            ((float4*)outz)[idx - nz4 - nw] = (float4){0.f, 0.f, 0.f, 0.f};
        }
    }
}

__global__ __launch_bounds__(256, 2)
void edge_mlp_kernel(const int* __restrict__ ei, const unsigned short* __restrict__ zb,
                     const unsigned short* __restrict__ w1s,
                     const float* __restrict__ b1, const float* __restrict__ W2,
                     const float* __restrict__ b2p, float* __restrict__ out, int E) {
    __shared__ unsigned short ldsA[2][64 * STRA];  // 2 x 33792 B (double buffer)
    __shared__ float ldsY[4 * 64];                 // per-wave GEMM2 partials

    const int tid  = threadIdx.x;
    const int lane = tid & 63;
    const int w    = tid >> 6;        // 0..3 : 64-h slice within this hy half
    const int l15  = lane & 15;
    const int l4   = lane >> 4;
    const int g    = tid >> 4;        // gather group
    const int l    = tid & 15;        // gather lane-in-row
    const int hy   = blockIdx.x;      // 0..1 : which 256-h half of H
    const int t0   = blockIdx.y * NT; // first tile index

    const unsigned aoff = l15 * STRA + l4 * 8;
    // hblk = hy*16 + w*4 + j;  B frag at w1s[(hblk*8 + kc)*512 + lane*8]
    const unsigned short* bp = w1s + ((hy * 16 + w * 4) * 8) * 512 + lane * 8;

    // prologue: gather tile 0 into buf 0
    gather_tile(ei, zb, &ldsA[0][0], t0 * 64, E, g, l);

    int cur = 0;
    #pragma unroll 1
    for (int t = 0; t < NT; ++t) {
        __syncthreads();              // buf[cur] ready; ldsY(t-1) consumed

        // issue next tile's gather now -> latency hides under this K-loop
        if (t + 1 < NT)
            gather_tile(ei, zb, &ldsA[cur ^ 1][0], (t0 + t + 1) * 64, E, g, l);

        const unsigned short* Ab = &ldsA[cur][0];

        f32x4 acc[4][4];
        #pragma unroll
        for (int i = 0; i < 4; i++)
            #pragma unroll
            for (int j = 0; j < 4; j++) acc[i][j] = (f32x4){0.f, 0.f, 0.f, 0.f};

        #pragma unroll
        for (int kc = 0; kc < 8; ++kc) {
            uint4 b[4];
            #pragma unroll
            for (int j = 0; j < 4; j++)
                b[j] = *(const uint4*)(bp + (j * 8 + kc) * 512);
            bf16x8 a[4];
            #pragma unroll
            for (int i = 0; i < 4; i++)
                a[i] = *(const bf16x8*)&Ab[aoff + i * 16 * STRA + kc * 32];
            #pragma unroll
            for (int i = 0; i < 4; i++)
                #pragma unroll
                for (int j = 0; j < 4; j++)
                    acc[i][j] = __builtin_amdgcn_mfma_f32_16x16x32_bf16(
                        a[i], *(const bf16x8*)&b[j], acc[i][j], 0, 0, 0);
        }

        // fused epilogue: h = relu(acc + b1); y = sum_h h * W2[h]
        float y[4][4];
        #pragma unroll
        for (int j = 0; j < 4; j++) {
            int h = hy * 256 + w * 64 + j * 16 + l15;
            float w2v = W2[h];
            float b1v = b1[h];
            #pragma unroll
            for (int i = 0; i < 4; i++)
                #pragma unroll
                for (int r = 0; r < 4; r++) {
                    float hv = acc[i][j][r] + b1v;
                    float s = fmaxf(hv, 0.f) * w2v;
                    y[i][r] = (j == 0) ? s : y[i][r] + s;
                }
        }

        // reduce over the 16 h-lanes (C layout: col = lane&15)
        #pragma unroll
        for (int i = 0; i < 4; i++)
            #pragma unroll
            for (int r = 0; r < 4; r++) {
                float v = y[i][r];
                v += __shfl_xor(v, 1);
                v += __shfl_xor(v, 2);
                v += __shfl_xor(v, 4);
                v += __shfl_xor(v, 8);
                y[i][r] = v;
            }

        if (l15 == 0) {
            #pragma unroll
            for (int i = 0; i < 4; i++)
                #pragma unroll
                for (int r = 0; r < 4; r++) {
                    int m = i * 16 + l4 * 4 + r;   // C layout: row=(lane>>4)*4+reg
                    ldsY[w * 64 + m] = y[i][r];
                }
        }
        __syncthreads();              // ldsY ready (also drains in-flight gather safely)

        if (tid < 64) {
            int e = (t0 + t) * 64 + tid;
            if (e < E) {
                float v = ldsY[tid] + ldsY[64 + tid] + ldsY[128 + tid] + ldsY[192 + tid];
                if (hy == 0) v += b2p[0];
                atomicAdd(&out[e], v);   // exactly 2 addends per e -> order-safe
            }
        }
        cur ^= 1;
    }
}

extern "C" void kernel_launch(void* const* d_in, const int* in_sizes, int n_in,
                              void* d_out, int out_size, void* d_ws, size_t ws_size,
                              hipStream_t stream) {
    const float* z  = (const float*)d_in[0];
    const int*   ei = (const int*)d_in[1];
    const float* W1 = (const float*)d_in[2];
    const float* b1 = (const float*)d_in[3];
    const float* W2 = (const float*)d_in[4];
    const float* b2 = (const float*)d_in[5];
    float* out = (float*)d_out;

    const int E  = in_sizes[1] / 2;   // 500000
    const int NZ = in_sizes[0];       // 6400000 = N*D

    unsigned short* zb  = (unsigned short*)d_ws;       // 12.8 MB
    unsigned short* w1s = zb + NZ;                     // 256 KB (swizzled W1)

    prep_kernel<<<2048, 256, 0, stream>>>(z, W1, zb, w1s, out, NZ / 4, E / 4);

    const int tiles   = (E + 63) / 64;                 // 7813
    const int yblocks = (tiles + NT - 1) / NT;         // 977
    dim3 grid(2, yblocks);                             // hy fastest -> gather L2 dedup
    edge_mlp_kernel<<<grid, 256, 0, stream>>>(ei, zb, w1s, b1, W2, b2, out, E);
}

// Round 10
// 325.740 us; speedup vs baseline: 1.4556x; 1.1600x over previous
//
#include <hip/hip_runtime.h>

// y[e] = W2 . relu(W1 . concat(z[src[e]], z[dst[e]]) + b1) + b2
// N=50000, D=128, H=512, E=500000. Compute-bound: 131 GFLOP in GEMM1.
// R10: zero-VMEM K-loop pipeline. B (64h x 256k per wave) lives in 128 VGPRs
// loaded once per block; next tile's gather goes to 32 VGPRs (greg) issued
// right after this tile's ds_write+barrier. K-loop = ds_read a + MFMA only,
// so nothing waits on the gather until the next ds_write (R9's lgkm-ordering
// trap avoided: no ds ops precede the K-loop's ds_reads in-queue).
// R7 bones kept: hy grid-split, 64x64 wave tile, padded LDS, atomicAdd.
// Budget: 128 B + 64 acc + 32 greg + misc ~= 250 <= 256 (bounds(256,2)).

typedef __bf16 bf16x8 __attribute__((ext_vector_type(8)));
typedef float f32x4 __attribute__((ext_vector_type(4)));

#define STRA 264   // 256 + 8 pad (ushort units)
#define NT 8       // 64-edge tiles per block

__device__ __forceinline__ unsigned short f2b(float f) {
    unsigned int u = __float_as_uint(f);
    u = (u + 0x7fffu + ((u >> 16) & 1u)) >> 16;   // RNE
    return (unsigned short)u;
}

// zb: z as bf16 [N][128].  w1s: W1 swizzled to MFMA-B fragment order:
// w1s[(hblk*8 + kc)*512 + lane*8 + t] = bf16(W1[hblk*16 + (lane&15)][kc*32 + (lane>>4)*8 + t])
// Also zeroes out[] (atomicAdd target).
__global__ void prep_kernel(const float* __restrict__ z, const float* __restrict__ W1,
                            unsigned short* __restrict__ zb, unsigned short* __restrict__ w1s,
                            float* __restrict__ outz, int nz4, int nout4) {
    int stride = gridDim.x * blockDim.x;
    const int nw = 256 * 64;   // (hblk*8+kc) x lane
    const int total = nz4 + nw + nout4;
    for (int idx = blockIdx.x * blockDim.x + threadIdx.x; idx < total; idx += stride) {
        if (idx < nz4) {
            float4 v = ((const float4*)z)[idx];
            ushort4 o;
            o.x = f2b(v.x); o.y = f2b(v.y); o.z = f2b(v.z); o.w = f2b(v.w);
            ((ushort4*)zb)[idx] = o;
        } else if (idx < nz4 + nw) {
            int u = idx - nz4;            // 0..16383
            int lane = u & 63;
            int blk  = u >> 6;            // hblk*8 + kc
            int h  = (blk >> 3) * 16 + (lane & 15);
            int kb = (blk & 7) * 32 + (lane >> 4) * 8;
            const float* src = W1 + h * 256 + kb;
            ushort4 o0, o1;
            float4 v0 = *(const float4*)(src);
            float4 v1 = *(const float4*)(src + 4);
            o0.x = f2b(v0.x); o0.y = f2b(v0.y); o0.z = f2b(v0.z); o0.w = f2b(v0.w);
            o1.x = f2b(v1.x); o1.y = f2b(v1.y); o1.z = f2b(v1.z); o1.w = f2b(v1.w);
            ushort4* dst = (ushort4*)(w1s + u * 8);
            dst[0] = o0; dst[1] = o1;
        } else {
            ((float4*)outz)[idx - nz4 - nw] = (float4){0.f, 0.f, 0.f, 0.f};
        }
    }
}

__global__ __launch_bounds__(256, 2)
void edge_mlp_kernel(const int* __restrict__ ei, const unsigned short* __restrict__ zb,
                     const unsigned short* __restrict__ w1s,
                     const float* __restrict__ b1, const float* __restrict__ W2,
                     const float* __restrict__ b2p, float* __restrict__ out, int E) {
    __shared__ unsigned short ldsA[64 * STRA];   // 33792 B, single buffer
    __shared__ int ldsIdx[2 * NT * 64];          // [side][512] : 4 KB
    __shared__ float ldsY[4 * 64];               // per-wave GEMM2 partials

    const int tid  = threadIdx.x;
    const int lane = tid & 63;
    const int w    = tid >> 6;        // 0..3 : 64-h slice within this hy half
    const int l15  = lane & 15;
    const int l4   = lane >> 4;
    const int g    = tid >> 4;        // gather group (16 groups)
    const int l    = tid & 15;        // gather lane-in-row
    const int hy   = blockIdx.x;      // 0..1 : which 256-h half of H
    const int t0e  = blockIdx.y * (NT * 64);   // first edge of this block

    // ---- preload B: wave's 64h x 256k as 32 bf16x8 fragments (128 VGPRs) ----
    bf16x8 breg[4][8];
    {
        const unsigned short* bb = w1s + ((hy * 16 + w * 4) * 8) * 512 + lane * 8;
        #pragma unroll
        for (int j = 0; j < 4; j++)
            #pragma unroll
            for (int kc = 0; kc < 8; kc++)
                breg[j][kc] = *(const bf16x8*)(bb + (j * 8 + kc) * 512);
    }

    // ---- preload all edge indices for the block's NT tiles ----
    #pragma unroll
    for (int k = 0; k < 4; k++) {
        int p = tid + k * 256;        // 0..1023 = side*512 + eo
        int side = p >> 9;
        int eo = p & 511;
        int e = t0e + eo;
        ldsIdx[p] = (e < E) ? ei[side * E + e] : 0;
    }
    __syncthreads();

    // ---- gather tile 0 into registers ----
    uint4 greg[8];
    #pragma unroll
    for (int it = 0; it < 8; ++it) {
        int hr = it * 16 + g, m = hr >> 1, side = hr & 1;
        int row = ldsIdx[side * 512 + m];
        greg[it] = *((const uint4*)(zb + (row << 7)) + l);
    }

    const unsigned aoff = l15 * STRA + l4 * 8;

    #pragma unroll 1
    for (int t = 0; t < NT; ++t) {
        // stage tile t (greg -> ldsA); prior barrier guarantees ldsA is free
        #pragma unroll
        for (int it = 0; it < 8; ++it) {
            int hr = it * 16 + g, m = hr >> 1, side = hr & 1;
            *(uint4*)&ldsA[m * STRA + side * 128 + l * 8] = greg[it];
        }
        __syncthreads();              // ldsA(t) visible

        // issue tile t+1's gather; nothing waits on it until next ds_write
        if (t + 1 < NT) {
            #pragma unroll
            for (int it = 0; it < 8; ++it) {
                int hr = it * 16 + g, m = hr >> 1, side = hr & 1;
                int row = ldsIdx[side * 512 + (t + 1) * 64 + m];
                greg[it] = *((const uint4*)(zb + (row << 7)) + l);
            }
        }

        // ---- K-loop: pure ds_read + MFMA (B from regs) ----
        f32x4 acc[4][4];
        #pragma unroll
        for (int i = 0; i < 4; i++)
            #pragma unroll
            for (int j = 0; j < 4; j++) acc[i][j] = (f32x4){0.f, 0.f, 0.f, 0.f};

        #pragma unroll
        for (int kc = 0; kc < 8; ++kc) {
            bf16x8 a[4];
            #pragma unroll
            for (int i = 0; i < 4; i++)
                a[i] = *(const bf16x8*)&ldsA[aoff + i * 16 * STRA + kc * 32];
            #pragma unroll
            for (int i = 0; i < 4; i++)
                #pragma unroll
                for (int j = 0; j < 4; j++)
                    acc[i][j] = __builtin_amdgcn_mfma_f32_16x16x32_bf16(
                        a[i], breg[j][kc], acc[i][j], 0, 0, 0);
        }

        // fused epilogue: h = relu(acc + b1); y = sum_h h * W2[h]
        float y[4][4];
        #pragma unroll
        for (int j = 0; j < 4; j++) {
            int h = hy * 256 + w * 64 + j * 16 + l15;
            float w2v = W2[h];
            float b1v = b1[h];
            #pragma unroll
            for (int i = 0; i < 4; i++)
                #pragma unroll
                for (int r = 0; r < 4; r++) {
                    float hv = acc[i][j][r] + b1v;
                    float s = fmaxf(hv, 0.f) * w2v;
                    y[i][r] = (j == 0) ? s : y[i][r] + s;
                }
        }

        // reduce over the 16 h-lanes (C layout: col = lane&15)
        #pragma unroll
        for (int i = 0; i < 4; i++)
            #pragma unroll
            for (int r = 0; r < 4; r++) {
                float v = y[i][r];
                v += __shfl_xor(v, 1);
                v += __shfl_xor(v, 2);
                v += __shfl_xor(v, 4);
                v += __shfl_xor(v, 8);
                y[i][r] = v;
            }

        if (l15 == 0) {
            #pragma unroll
            for (int i = 0; i < 4; i++)
                #pragma unroll
                for (int r = 0; r < 4; r++) {
                    int m = i * 16 + l4 * 4 + r;   // C layout: row=(lane>>4)*4+reg
                    ldsY[w * 64 + m] = y[i][r];
                }
        }
        __syncthreads();              // ldsY visible; ldsA free for next ds_write

        if (tid < 64) {
            int e = t0e + t * 64 + tid;
            if (e < E) {
                float v = ldsY[tid] + ldsY[64 + tid] + ldsY[128 + tid] + ldsY[192 + tid];
                if (hy == 0) v += b2p[0];
                atomicAdd(&out[e], v);   // exactly 2 addends per e -> order-safe
            }
        }
    }
}

extern "C" void kernel_launch(void* const* d_in, const int* in_sizes, int n_in,
                              void* d_out, int out_size, void* d_ws, size_t ws_size,
                              hipStream_t stream) {
    const float* z  = (const float*)d_in[0];
    const int*   ei = (const int*)d_in[1];
    const float* W1 = (const float*)d_in[2];
    const float* b1 = (const float*)d_in[3];
    const float* W2 = (const float*)d_in[4];
    const float* b2 = (const float*)d_in[5];
    float* out = (float*)d_out;

    const int E  = in_sizes[1] / 2;   // 500000
    const int NZ = in_sizes[0];       // 6400000 = N*D

    unsigned short* zb  = (unsigned short*)d_ws;       // 12.8 MB
    unsigned short* w1s = zb + NZ;                     // 256 KB (swizzled W1)

    prep_kernel<<<2048, 256, 0, stream>>>(z, W1, zb, w1s, out, NZ / 4, E / 4);

    const int tiles   = (E + 63) / 64;                 // 7813
    const int yblocks = (tiles + NT - 1) / NT;         // 977
    dim3 grid(2, yblocks);
    edge_mlp_kernel<<<grid, 256, 0, stream>>>(ei, zb, w1s, b1, W2, b2, out, E);
}